// Round 1
// baseline (344.444 us; speedup 1.0000x reference)
//
#include <hip/hip_runtime.h>
#include <hip/hip_bf16.h>
#include <math.h>

// CodecAttention: x->QKV proj (bf16 MFMA) -> RMSNorm(q,k) -> sliding-window
// ALiBi attention (win=16) -> out proj. B=4 T=2048 DIM=1024 H=8 D=128.

#define TSEQ 2048
#define DIMW 1024
#define NHEAD 8
#define WIN 16

typedef __bf16 bf16x8_t __attribute__((ext_vector_type(8)));
typedef float f32x4_t __attribute__((ext_vector_type(4)));

__device__ __forceinline__ unsigned short f2bf(float f) {
  unsigned u = __float_as_uint(f);
  u += 0x7fffu + ((u >> 16) & 1u);   // round-to-nearest-even
  return (unsigned short)(u >> 16);
}
__device__ __forceinline__ float bflo(unsigned u) { return __uint_as_float(u << 16); }
__device__ __forceinline__ float bfhi(unsigned u) { return __uint_as_float(u & 0xffff0000u); }

// ---------- f32 -> bf16 conversion of x ----------
__global__ __launch_bounds__(256)
void k_conv_x(const float* __restrict__ x, unsigned short* __restrict__ xb, int n4) {
  int i = blockIdx.x * 256 + threadIdx.x;
  if (i >= n4) return;
  float4 v = ((const float4*)x)[i];
  ushort4 o;
  o.x = f2bf(v.x); o.y = f2bf(v.y); o.z = f2bf(v.z); o.w = f2bf(v.w);
  ((ushort4*)xb)[i] = o;
}

// ---------- transpose + convert weights: Wt[z][n][k] = w_z[k][n] ----------
__global__ __launch_bounds__(256)
void k_conv_w(const float* __restrict__ wq, const float* __restrict__ wk,
              const float* __restrict__ wv, const float* __restrict__ wo,
              unsigned short* __restrict__ Wt) {
  __shared__ float tile[32][33];
  const int z = blockIdx.z;
  const float* src = (z == 0) ? wq : (z == 1) ? wk : (z == 2) ? wv : wo;
  const int n0 = blockIdx.x * 32;
  const int k0 = blockIdx.y * 32;
  const int tx = threadIdx.x, ty = threadIdx.y;  // 32 x 8
#pragma unroll
  for (int i = 0; i < 4; ++i)
    tile[ty + 8 * i][tx] = src[(size_t)(k0 + ty + 8 * i) * DIMW + n0 + tx];
  __syncthreads();
#pragma unroll
  for (int i = 0; i < 4; ++i)
    Wt[(size_t)z * DIMW * DIMW + (size_t)(n0 + ty + 8 * i) * DIMW + k0 + tx] =
        f2bf(tile[tx][ty + 8 * i]);
}

// ---------- bf16 TN GEMM: C[M][N] = A[M][K] * Bt[N][K]^T ----------
// m97 structure: 128x128 tile, BK=32, 4 waves (2x2 of 64x64), 16x16x32 MFMA,
// global_load_lds width 16 with pre-swizzled source (rule 21), swizzled
// ds_read_b128 (2-way conflict = free).
#define GLDS(gp, lp)                                                        \
  __builtin_amdgcn_global_load_lds(                                         \
      (const __attribute__((address_space(1))) void*)(gp),                  \
      (__attribute__((address_space(3))) void*)(lp), 16, 0, 0)

template <int OUTF32>
__global__ __launch_bounds__(256)
void k_gemm(const unsigned short* __restrict__ A,   // [M][K] bf16
            const unsigned short* __restrict__ Bt,  // [N][K] bf16
            unsigned short* __restrict__ Cb,        // bf16 out (OUTF32==0)
            float* __restrict__ Cf,                 // f32 out  (OUTF32==1)
            int M, int N, int K) {
  __shared__ __align__(16) unsigned char smem[16384];
  unsigned char* ldsA = smem;
  unsigned char* ldsB = smem + 8192;
  const int tid = threadIdx.x;
  const int lane = tid & 63;
  const int w = tid >> 6;          // wave 0..3
  const int wr = w >> 1, wc = w & 1;
  const int bx = blockIdx.x, by = blockIdx.y;

  // Staging: LDS linear slot (row, g) holds global k-group kg = g ^ ((row>>1)&3).
  // Per wave, issue i covers LDS bytes [(i*4+w)*1024, +1024): row=(i*4+w)*16+(l>>2), g=l&3.
  const int kgsrc = (((lane & 3) ^ ((lane >> 3) & 3))) * 8;  // elements
  const int rloc = w * 16 + (lane >> 2);
  const size_t aOff0 = (size_t)(by * 128 + rloc) * K + kgsrc;
  const size_t aOff1 = (size_t)(by * 128 + rloc + 64) * K + kgsrc;
  const size_t bOff0 = (size_t)(bx * 128 + rloc) * K + kgsrc;
  const size_t bOff1 = (size_t)(bx * 128 + rloc + 64) * K + kgsrc;
  unsigned char* dstA0 = ldsA + w * 1024;
  unsigned char* dstA1 = ldsA + (4 + w) * 1024;
  unsigned char* dstB0 = ldsB + w * 1024;
  unsigned char* dstB1 = ldsB + (4 + w) * 1024;

  // Fragment reads: row = w?*64 + frag*16 + (lane&15); kg = lane>>4;
  // slot = kg ^ ((row>>1)&3) = (lane>>4) ^ ((lane>>1)&3)   (frag*16 rows -> no effect mod 4)
  const int swz = ((lane >> 4) ^ ((lane >> 1) & 3)) * 16;
  const int aRd = (wr * 64 + (lane & 15)) * 64 + swz;
  const int bRd = (wc * 64 + (lane & 15)) * 64 + swz;

  f32x4_t acc[4][4];
#pragma unroll
  for (int m = 0; m < 4; ++m)
#pragma unroll
    for (int n = 0; n < 4; ++n) acc[m][n] = (f32x4_t){0.f, 0.f, 0.f, 0.f};

  const int nkt = K >> 5;
  for (int kt = 0; kt < nkt; ++kt) {
    const int k0 = kt << 5;
    __syncthreads();  // previous iter's reads done before overwrite
    GLDS(A + aOff0 + k0, dstA0);
    GLDS(A + aOff1 + k0, dstA1);
    GLDS(Bt + bOff0 + k0, dstB0);
    GLDS(Bt + bOff1 + k0, dstB1);
    __syncthreads();  // drains vmcnt(0): tile resident
    bf16x8_t af[4], bfr[4];
#pragma unroll
    for (int m = 0; m < 4; ++m) af[m] = *(const bf16x8_t*)(ldsA + aRd + m * 1024);
#pragma unroll
    for (int n = 0; n < 4; ++n) bfr[n] = *(const bf16x8_t*)(ldsB + bRd + n * 1024);
#pragma unroll
    for (int m = 0; m < 4; ++m)
#pragma unroll
      for (int n = 0; n < 4; ++n)
        acc[m][n] = __builtin_amdgcn_mfma_f32_16x16x32_bf16(af[m], bfr[n], acc[m][n], 0, 0, 0);
  }

  // C/D layout (m89-verified): col = lane&15, row = (lane>>4)*4 + reg
  const int row0 = by * 128 + wr * 64 + ((lane >> 4) << 2);
  const int col0 = bx * 128 + wc * 64 + (lane & 15);
#pragma unroll
  for (int m = 0; m < 4; ++m)
#pragma unroll
    for (int n = 0; n < 4; ++n)
#pragma unroll
      for (int r = 0; r < 4; ++r) {
        const int row = row0 + m * 16 + r;
        const int col = col0 + n * 16;
        if (OUTF32)
          Cf[(size_t)row * N + col] = acc[m][n][r];
        else
          Cb[(size_t)row * N + col] = f2bf(acc[m][n][r]);
      }
}

// ---------- in-place RMSNorm on q (cols 0..1023) and k (cols 1024..2047) ----------
__global__ __launch_bounds__(256)
void k_rmsnorm(unsigned short* __restrict__ qkv, const float* __restrict__ qw,
               const float* __restrict__ kw) {
  const int row = blockIdx.x;
  const int tid = threadIdx.x;
  unsigned short* base = qkv + (size_t)row * 3072;
  uint2 uq = *(const uint2*)(base + tid * 4);
  uint2 uk = *(const uint2*)(base + 1024 + tid * 4);
  float q0 = bflo(uq.x), q1 = bfhi(uq.x), q2 = bflo(uq.y), q3 = bfhi(uq.y);
  float k0 = bflo(uk.x), k1 = bfhi(uk.x), k2 = bflo(uk.y), k3 = bfhi(uk.y);
  float sq = q0 * q0 + q1 * q1 + q2 * q2 + q3 * q3;
  float sk = k0 * k0 + k1 * k1 + k2 * k2 + k3 * k3;
#pragma unroll
  for (int off = 32; off > 0; off >>= 1) {
    sq += __shfl_xor(sq, off);
    sk += __shfl_xor(sk, off);
  }
  __shared__ float red[8];
  const int w = tid >> 6;
  if ((tid & 63) == 0) { red[w] = sq; red[4 + w] = sk; }
  __syncthreads();
  sq = red[0] + red[1] + red[2] + red[3];
  sk = red[4] + red[5] + red[6] + red[7];
  const float rq = rsqrtf(sq * (1.0f / 1024.0f) + 1e-6f);
  const float rk = rsqrtf(sk * (1.0f / 1024.0f) + 1e-6f);
  const int c = tid * 4;
  uint2 oq, ok;
  oq.x = (unsigned)f2bf(q0 * rq * qw[c]) | ((unsigned)f2bf(q1 * rq * qw[c + 1]) << 16);
  oq.y = (unsigned)f2bf(q2 * rq * qw[c + 2]) | ((unsigned)f2bf(q3 * rq * qw[c + 3]) << 16);
  ok.x = (unsigned)f2bf(k0 * rk * kw[c]) | ((unsigned)f2bf(k1 * rk * kw[c + 1]) << 16);
  ok.y = (unsigned)f2bf(k2 * rk * kw[c + 2]) | ((unsigned)f2bf(k3 * rk * kw[c + 3]) << 16);
  *(uint2*)(base + tid * 4) = oq;
  *(uint2*)(base + 1024 + tid * 4) = ok;
}

// ---------- sliding-window ALiBi attention: one wave per (b,h,t) ----------
__global__ __launch_bounds__(256)
void k_attn(const unsigned short* __restrict__ qkv, unsigned short* __restrict__ outb) {
  const int lane = threadIdx.x & 63;
  const int wv = threadIdx.x >> 6;
  const int wid = blockIdx.x * 4 + wv;       // [0, 65536)
  const int bh = wid >> 11;                  // t-fast: adjacent waves share K/V window
  const int t = wid & 2047;
  const int b = bh >> 3;
  const int h = bh & 7;
  const int r = b * TSEQ + t;
  const unsigned* qp = (const unsigned*)(qkv + (size_t)r * 3072 + h * 128);
  const unsigned qraw = qp[lane];
  const float q0 = bflo(qraw), q1 = bfhi(qraw);
  const int jlo = (t >= WIN) ? (t - WIN) : 0;
  const int cnt = t - jlo + 1;               // <= 17
  const float scale = 0.08838834764831845f;  // 1/sqrt(128)
  const float slope = 1.0f / (float)(1 << h);
  float sc = 0.0f;
  for (int l = 0; l < cnt; ++l) {
    const int j = jlo + l;
    const unsigned kraw =
        *((const unsigned*)(qkv + (size_t)(b * TSEQ + j) * 3072 + 1024 + h * 128) + lane);
    float p = q0 * bflo(kraw) + q1 * bfhi(kraw);
#pragma unroll
    for (int off = 32; off > 0; off >>= 1) p += __shfl_xor(p, off);
    if (lane == l) sc = p;
  }
  float val = (lane < cnt) ? (sc * scale + slope * (float)(jlo + lane - t)) : -3.0e38f;
  float mx = val;
#pragma unroll
  for (int off = 32; off > 0; off >>= 1) mx = fmaxf(mx, __shfl_xor(mx, off));
  const float e = (lane < cnt) ? __expf(val - mx) : 0.0f;
  float s = e;
#pragma unroll
  for (int off = 32; off > 0; off >>= 1) s += __shfl_xor(s, off);
  const float inv = 1.0f / s;
  float y0 = 0.f, y1 = 0.f;
  for (int l = 0; l < cnt; ++l) {
    const float wgt = __shfl(e, l) * inv;
    const unsigned vraw =
        *((const unsigned*)(qkv + (size_t)(b * TSEQ + jlo + l) * 3072 + 2048 + h * 128) + lane);
    y0 += wgt * bflo(vraw);
    y1 += wgt * bfhi(vraw);
  }
  const unsigned o = (unsigned)f2bf(y0) | ((unsigned)f2bf(y1) << 16);
  ((unsigned*)(outb + (size_t)r * 1024 + h * 128))[lane] = o;
}

extern "C" void kernel_launch(void* const* d_in, const int* in_sizes, int n_in,
                              void* d_out, int out_size, void* d_ws, size_t ws_size,
                              hipStream_t stream) {
  const float* x = (const float*)d_in[0];
  const float* wq = (const float*)d_in[1];
  const float* wk = (const float*)d_in[2];
  const float* wv = (const float*)d_in[3];
  const float* wo = (const float*)d_in[4];
  const float* qnw = (const float*)d_in[5];
  const float* knw = (const float*)d_in[6];
  float* out = (float*)d_out;

  const int M = 4 * TSEQ;  // 8192 rows
  // workspace layout (75.5 MB):
  //   xb   [M][1024] bf16 (16.78 MB)  -- x in bf16; later reused as attention output
  //   Wt   [4][1024][1024] bf16 (8.39 MB) -- transposed wq,wk,wv,wo
  //   xqkv [M][3072] bf16 (50.33 MB)  -- q|k|v (q,k normalized in place)
  unsigned short* xb = (unsigned short*)d_ws;
  unsigned short* Wt = xb + (size_t)M * DIMW;
  unsigned short* xqkv = Wt + (size_t)4 * DIMW * DIMW;
  if (ws_size < ((size_t)M * DIMW + (size_t)4 * DIMW * DIMW + (size_t)M * 3072) * 2) return;

  k_conv_x<<<(M * DIMW / 4 + 255) / 256, 256, 0, stream>>>(x, xb, M * DIMW / 4);
  k_conv_w<<<dim3(32, 32, 4), dim3(32, 8), 0, stream>>>(wq, wk, wv, wo, Wt);
  k_gemm<0><<<dim3(24, 64), 256, 0, stream>>>(xb, Wt, xqkv, nullptr, M, 3072, 1024);
  k_rmsnorm<<<M, 256, 0, stream>>>(xqkv, qnw, knw);
  k_attn<<<M * NHEAD / 4, 256, 0, stream>>>(xqkv, xb);  // xb now attention output
  k_gemm<1><<<dim3(8, 64), 256, 0, stream>>>(xb, Wt + (size_t)3 * DIMW * DIMW, nullptr, out,
                                             M, 1024, 1024);
}

// Round 2
// 258.081 us; speedup vs baseline: 1.3346x; 1.3346x over previous
//
#include <hip/hip_runtime.h>
#include <hip/hip_bf16.h>
#include <math.h>

// CodecAttention: x->QKV proj (bf16 MFMA, V written transposed) -> RMSNorm(q,k)
// -> MFMA sliding-window ALiBi attention (win=16) -> out proj.
// B=4 T=2048 DIM=1024 H=8 D=128.

#define TSEQ 2048
#define DIMW 1024
#define NHEAD 8
#define WIN 16

typedef __bf16 bf16x8_t __attribute__((ext_vector_type(8)));
typedef float f32x4_t __attribute__((ext_vector_type(4)));

__device__ __forceinline__ unsigned short f2bf(float f) {
  unsigned u = __float_as_uint(f);
  u += 0x7fffu + ((u >> 16) & 1u);   // round-to-nearest-even
  return (unsigned short)(u >> 16);
}
__device__ __forceinline__ float bflo(unsigned u) { return __uint_as_float(u << 16); }
__device__ __forceinline__ float bfhi(unsigned u) { return __uint_as_float(u & 0xffff0000u); }

// ---------- f32 -> bf16 conversion of x ----------
__global__ __launch_bounds__(256)
void k_conv_x(const float* __restrict__ x, unsigned short* __restrict__ xb, int n4) {
  int i = blockIdx.x * 256 + threadIdx.x;
  if (i >= n4) return;
  float4 v = ((const float4*)x)[i];
  ushort4 o;
  o.x = f2bf(v.x); o.y = f2bf(v.y); o.z = f2bf(v.z); o.w = f2bf(v.w);
  ((ushort4*)xb)[i] = o;
}

// ---------- transpose + convert weights: Wt[z][n][k] = w_z[k][n] ----------
__global__ __launch_bounds__(256)
void k_conv_w(const float* __restrict__ wq, const float* __restrict__ wk,
              const float* __restrict__ wv, const float* __restrict__ wo,
              unsigned short* __restrict__ Wt) {
  __shared__ float tile[32][33];
  const int z = blockIdx.z;
  const float* src = (z == 0) ? wq : (z == 1) ? wk : (z == 2) ? wv : wo;
  const int n0 = blockIdx.x * 32;
  const int k0 = blockIdx.y * 32;
  const int tx = threadIdx.x, ty = threadIdx.y;  // 32 x 8
#pragma unroll
  for (int i = 0; i < 4; ++i)
    tile[ty + 8 * i][tx] = src[(size_t)(k0 + ty + 8 * i) * DIMW + n0 + tx];
  __syncthreads();
#pragma unroll
  for (int i = 0; i < 4; ++i)
    Wt[(size_t)z * DIMW * DIMW + (size_t)(n0 + ty + 8 * i) * DIMW + k0 + tx] =
        f2bf(tile[tx][ty + 8 * i]);
}

// ---------- bf16 TN GEMM: C[M][N] = A[M][K] * Bt[N][K]^T ----------
// m97 structure: 128x128 tile, BK=32, 4 waves (2x2 of 64x64), 16x16x32 MFMA,
// global_load_lds width 16 with pre-swizzled source (rule 21), swizzled
// ds_read_b128 (2-way conflict = free).
// MODE 0: bf16 out; cols<2048 -> Cb[row][2048], cols>=2048 (the V third)
//         written TRANSPOSED into Vt[(b*8+h)*128+d][t].
// MODE 1: f32 out Cf[row][N].
#define GLDS(gp, lp)                                                        \
  __builtin_amdgcn_global_load_lds(                                         \
      (const __attribute__((address_space(1))) void*)(gp),                  \
      (__attribute__((address_space(3))) void*)(lp), 16, 0, 0)

template <int MODE>
__global__ __launch_bounds__(256)
void k_gemm(const unsigned short* __restrict__ A,   // [M][K] bf16
            const unsigned short* __restrict__ Bt,  // [N][K] bf16
            unsigned short* __restrict__ Cb,        // bf16 out (MODE 0, q|k part)
            unsigned short* __restrict__ Vt,        // bf16 out (MODE 0, v part, transposed)
            float* __restrict__ Cf,                 // f32 out  (MODE 1)
            int M, int N, int K) {
  __shared__ __align__(16) unsigned char smem[16384];
  unsigned char* ldsA = smem;
  unsigned char* ldsB = smem + 8192;
  const int tid = threadIdx.x;
  const int lane = tid & 63;
  const int w = tid >> 6;          // wave 0..3
  const int wr = w >> 1, wc = w & 1;
  const int bx = blockIdx.x, by = blockIdx.y;

  // Staging: LDS linear slot (row, g) holds global k-group kg = g ^ ((row>>1)&3).
  const int kgsrc = (((lane & 3) ^ ((lane >> 3) & 3))) * 8;  // elements
  const int rloc = w * 16 + (lane >> 2);
  const size_t aOff0 = (size_t)(by * 128 + rloc) * K + kgsrc;
  const size_t aOff1 = (size_t)(by * 128 + rloc + 64) * K + kgsrc;
  const size_t bOff0 = (size_t)(bx * 128 + rloc) * K + kgsrc;
  const size_t bOff1 = (size_t)(bx * 128 + rloc + 64) * K + kgsrc;
  unsigned char* dstA0 = ldsA + w * 1024;
  unsigned char* dstA1 = ldsA + (4 + w) * 1024;
  unsigned char* dstB0 = ldsB + w * 1024;
  unsigned char* dstB1 = ldsB + (4 + w) * 1024;

  // Fragment reads: slot = (lane>>4) ^ ((lane>>1)&3)
  const int swz = ((lane >> 4) ^ ((lane >> 1) & 3)) * 16;
  const int aRd = (wr * 64 + (lane & 15)) * 64 + swz;
  const int bRd = (wc * 64 + (lane & 15)) * 64 + swz;

  f32x4_t acc[4][4];
#pragma unroll
  for (int m = 0; m < 4; ++m)
#pragma unroll
    for (int n = 0; n < 4; ++n) acc[m][n] = (f32x4_t){0.f, 0.f, 0.f, 0.f};

  const int nkt = K >> 5;
  for (int kt = 0; kt < nkt; ++kt) {
    const int k0 = kt << 5;
    __syncthreads();  // previous iter's reads done before overwrite
    GLDS(A + aOff0 + k0, dstA0);
    GLDS(A + aOff1 + k0, dstA1);
    GLDS(Bt + bOff0 + k0, dstB0);
    GLDS(Bt + bOff1 + k0, dstB1);
    __syncthreads();  // drains vmcnt(0): tile resident
    bf16x8_t af[4], bfr[4];
#pragma unroll
    for (int m = 0; m < 4; ++m) af[m] = *(const bf16x8_t*)(ldsA + aRd + m * 1024);
#pragma unroll
    for (int n = 0; n < 4; ++n) bfr[n] = *(const bf16x8_t*)(ldsB + bRd + n * 1024);
#pragma unroll
    for (int m = 0; m < 4; ++m)
#pragma unroll
      for (int n = 0; n < 4; ++n)
        acc[m][n] = __builtin_amdgcn_mfma_f32_16x16x32_bf16(af[m], bfr[n], acc[m][n], 0, 0, 0);
  }

  // C/D layout (m89-verified): col = lane&15, row = (lane>>4)*4 + reg
  const int row0 = by * 128 + wr * 64 + ((lane >> 4) << 2);
  const int col0 = bx * 128 + wc * 64 + (lane & 15);
#pragma unroll
  for (int m = 0; m < 4; ++m)
#pragma unroll
    for (int n = 0; n < 4; ++n)
#pragma unroll
      for (int r = 0; r < 4; ++r) {
        const int row = row0 + m * 16 + r;
        const int col = col0 + n * 16;
        const float v = acc[m][n][r];
        if (MODE == 1) {
          Cf[(size_t)row * N + col] = v;
        } else if (col < 2048) {
          Cb[(size_t)row * 2048 + col] = f2bf(v);
        } else {
          const int vcol = col - 2048;
          const int hh = vcol >> 7, dd = vcol & 127;
          const int bb = row >> 11, tt = row & 2047;
          Vt[((size_t)(bb * NHEAD + hh) * 128 + dd) * TSEQ + tt] = f2bf(v);
        }
      }
}

// ---------- in-place RMSNorm on q (cols 0..1023) and k (cols 1024..2047) ----------
__global__ __launch_bounds__(256)
void k_rmsnorm(unsigned short* __restrict__ qk, const float* __restrict__ qw,
               const float* __restrict__ kw) {
  const int row = blockIdx.x;
  const int tid = threadIdx.x;
  unsigned short* base = qk + (size_t)row * 2048;
  uint2 uq = *(const uint2*)(base + tid * 4);
  uint2 uk = *(const uint2*)(base + 1024 + tid * 4);
  float q0 = bflo(uq.x), q1 = bfhi(uq.x), q2 = bflo(uq.y), q3 = bfhi(uq.y);
  float k0 = bflo(uk.x), k1 = bfhi(uk.x), k2 = bflo(uk.y), k3 = bfhi(uk.y);
  float sq = q0 * q0 + q1 * q1 + q2 * q2 + q3 * q3;
  float sk = k0 * k0 + k1 * k1 + k2 * k2 + k3 * k3;
#pragma unroll
  for (int off = 32; off > 0; off >>= 1) {
    sq += __shfl_xor(sq, off);
    sk += __shfl_xor(sk, off);
  }
  __shared__ float red[8];
  const int w = tid >> 6;
  if ((tid & 63) == 0) { red[w] = sq; red[4 + w] = sk; }
  __syncthreads();
  sq = red[0] + red[1] + red[2] + red[3];
  sk = red[4] + red[5] + red[6] + red[7];
  const float rq = rsqrtf(sq * (1.0f / 1024.0f) + 1e-6f);
  const float rk = rsqrtf(sk * (1.0f / 1024.0f) + 1e-6f);
  const int c = tid * 4;
  uint2 oq, ok;
  oq.x = (unsigned)f2bf(q0 * rq * qw[c]) | ((unsigned)f2bf(q1 * rq * qw[c + 1]) << 16);
  oq.y = (unsigned)f2bf(q2 * rq * qw[c + 2]) | ((unsigned)f2bf(q3 * rq * qw[c + 3]) << 16);
  ok.x = (unsigned)f2bf(k0 * rk * kw[c]) | ((unsigned)f2bf(k1 * rk * kw[c + 1]) << 16);
  ok.y = (unsigned)f2bf(k2 * rk * kw[c + 2]) | ((unsigned)f2bf(k3 * rk * kw[c + 3]) << 16);
  *(uint2*)(base + tid * 4) = oq;
  *(uint2*)(base + 1024 + tid * 4) = ok;
}

// ---------- MFMA sliding-window ALiBi attention ----------
// One wave per 16 queries of one (b,h). Key window: 32 keys [t0-16, t0+16).
// Swapped QK^T (A=K, B=Q) -> S^T: lane holds query c=lane&15, keys g*4+r (+16).
// Softmax: in-lane over 8 + shfl_xor(16,32). P -> padded LDS -> A-frag for PV.
// V read from transposed Vt buffer as b128 B-frags.
__global__ __launch_bounds__(256)
void k_attn(const unsigned short* __restrict__ qk,   // [8192][2048] q|k (normalized)
            const unsigned short* __restrict__ vt,   // [(b*8+h)*128+d][2048]
            unsigned short* __restrict__ outb) {     // [8192][1024] bf16
  __shared__ __align__(16) unsigned char plds_all[4][1280];  // 16 rows x 80B (40 elems)
  const int lane = threadIdx.x & 63;
  const int wv = threadIdx.x >> 6;
  unsigned char* plds = plds_all[wv];
  const int bh = blockIdx.y;                 // 0..31
  const int b = bh >> 3, h = bh & 7;
  const int t0 = blockIdx.x * 64 + wv * 16;
  const int g = lane >> 4, c = lane & 15;
  const int jlo = t0 - 16;

  // Q B-fragments: Q[t0+c][kc*32 + g*8 .. +8]
  const unsigned short* qrow = qk + (size_t)(b * TSEQ + t0 + c) * 2048 + h * 128 + g * 8;
  bf16x8_t qf[4];
#pragma unroll
  for (int kc = 0; kc < 4; ++kc) qf[kc] = *(const bf16x8_t*)(qrow + kc * 32);

  // K A-fragments (2 key-tiles); clamp negative rows (masked anyway)
  const int j0 = jlo + c;
  const int j0c = (j0 < 0) ? 0 : j0;
  const unsigned short* krow0 = qk + (size_t)(b * TSEQ + j0c) * 2048 + 1024 + h * 128 + g * 8;
  const unsigned short* krow1 = qk + (size_t)(b * TSEQ + t0 + c) * 2048 + 1024 + h * 128 + g * 8;
  bf16x8_t kf0[4], kf1[4];
#pragma unroll
  for (int kc = 0; kc < 4; ++kc) {
    kf0[kc] = *(const bf16x8_t*)(krow0 + kc * 32);
    kf1[kc] = *(const bf16x8_t*)(krow1 + kc * 32);
  }

  f32x4_t s0 = (f32x4_t){0.f, 0.f, 0.f, 0.f};
  f32x4_t s1 = (f32x4_t){0.f, 0.f, 0.f, 0.f};
#pragma unroll
  for (int kc = 0; kc < 4; ++kc) {
    s0 = __builtin_amdgcn_mfma_f32_16x16x32_bf16(kf0[kc], qf[kc], s0, 0, 0, 0);
    s1 = __builtin_amdgcn_mfma_f32_16x16x32_bf16(kf1[kc], qf[kc], s1, 0, 0, 0);
  }

  // scores + mask + bias. key kk = z*16 + g*4 + r; query = c; rel = kk-16-c.
  const float scale = 0.08838834764831845f;  // 1/sqrt(128)
  const float slope = 1.0f / (float)(1 << h);
  float val[8];
#pragma unroll
  for (int z = 0; z < 2; ++z)
#pragma unroll
    for (int r = 0; r < 4; ++r) {
      const int kk = z * 16 + g * 4 + r;
      const int rel = kk - 16 - c;
      const bool ok = (rel <= 0) & (rel >= -WIN) & (jlo + kk >= 0);
      const float sc = (z == 0) ? s0[r] : s1[r];
      val[z * 4 + r] = ok ? (sc * scale + slope * (float)rel) : -1.0e30f;
    }
  float m = val[0];
#pragma unroll
  for (int i = 1; i < 8; ++i) m = fmaxf(m, val[i]);
  m = fmaxf(m, __shfl_xor(m, 16));
  m = fmaxf(m, __shfl_xor(m, 32));
  float e[8], s = 0.f;
#pragma unroll
  for (int i = 0; i < 8; ++i) { e[i] = __expf(val[i] - m); s += e[i]; }
  s += __shfl_xor(s, 16);
  s += __shfl_xor(s, 32);
  const float inv = 1.0f / s;

  // P -> LDS [query c][key kk], row stride 40 elems (80B): 2-way banks = free
#pragma unroll
  for (int z = 0; z < 2; ++z) {
    uint2 pk;
    pk.x = (unsigned)f2bf(e[z * 4 + 0] * inv) | ((unsigned)f2bf(e[z * 4 + 1] * inv) << 16);
    pk.y = (unsigned)f2bf(e[z * 4 + 2] * inv) | ((unsigned)f2bf(e[z * 4 + 3] * inv) << 16);
    *(uint2*)(plds + c * 80 + z * 32 + g * 8) = pk;
  }
  // A-fragment of P: row=c (query), keys g*8..+8
  const bf16x8_t pf = *(const bf16x8_t*)(plds + c * 80 + g * 16);

  // PV: B-frag = V[jlo + g*8 + i][d0 + c] = Vt[d0+c][jlo + g*8 ...]
  const int vc0 = jlo + g * 8;
  const int vcc = (vc0 < 0) ? 0 : vc0;   // garbage rows get zero weight
  const unsigned short* vbase = vt + (size_t)(bh * 128 + c) * TSEQ + vcc;
  unsigned short* orow = outb + (size_t)(b * TSEQ + t0) * 1024 + h * 128 + c;
#pragma unroll
  for (int n = 0; n < 8; ++n) {
    const bf16x8_t vf = *(const bf16x8_t*)(vbase + (size_t)n * 16 * TSEQ);
    f32x4_t o = __builtin_amdgcn_mfma_f32_16x16x32_bf16(pf, vf, (f32x4_t){0.f, 0.f, 0.f, 0.f},
                                                        0, 0, 0);
    // C: row=(g*4+r)=query, col=c=d within chunk n
#pragma unroll
    for (int r = 0; r < 4; ++r)
      orow[(size_t)(g * 4 + r) * 1024 + n * 16] = f2bf(o[r]);
  }
}

extern "C" void kernel_launch(void* const* d_in, const int* in_sizes, int n_in,
                              void* d_out, int out_size, void* d_ws, size_t ws_size,
                              hipStream_t stream) {
  const float* x = (const float*)d_in[0];
  const float* wq = (const float*)d_in[1];
  const float* wk = (const float*)d_in[2];
  const float* wv = (const float*)d_in[3];
  const float* wo = (const float*)d_in[4];
  const float* qnw = (const float*)d_in[5];
  const float* knw = (const float*)d_in[6];
  float* out = (float*)d_out;

  const int M = 4 * TSEQ;  // 8192 rows
  // workspace (75.5 MB):
  //   xb  [M][1024] bf16 (16.8 MB)  -- x bf16; later reused as attention output
  //   Wt  [4][1024][1024] bf16 (8.4 MB)
  //   qk  [M][2048] bf16 (33.5 MB)  -- q|k (normalized in place)
  //   Vt  [32][128][2048] bf16 (16.8 MB) -- V transposed per (b,h)
  unsigned short* xb = (unsigned short*)d_ws;
  unsigned short* Wt = xb + (size_t)M * DIMW;
  unsigned short* qkb = Wt + (size_t)4 * DIMW * DIMW;
  unsigned short* Vt = qkb + (size_t)M * 2048;
  if (ws_size < ((size_t)M * DIMW + (size_t)4 * DIMW * DIMW + (size_t)M * 2048 +
                 (size_t)M * 2048) * 2) return;

  k_conv_x<<<(M * DIMW / 4 + 255) / 256, 256, 0, stream>>>(x, xb, M * DIMW / 4);
  k_conv_w<<<dim3(32, 32, 4), dim3(32, 8), 0, stream>>>(wq, wk, wv, wo, Wt);
  k_gemm<0><<<dim3(24, 64), 256, 0, stream>>>(xb, Wt, qkb, Vt, nullptr, M, 3072, 1024);
  k_rmsnorm<<<M, 256, 0, stream>>>(qkb, qnw, knw);
  k_attn<<<dim3(TSEQ / 64, 32), 256, 0, stream>>>(qkb, Vt, xb);  // xb = attn out
  k_gemm<1><<<dim3(8, 64), 256, 0, stream>>>(xb, Wt + (size_t)3 * DIMW * DIMW, nullptr,
                                             nullptr, out, M, 1024, 1024);
}

// Round 3
// 241.039 us; speedup vs baseline: 1.4290x; 1.0707x over previous
//
#include <hip/hip_runtime.h>
#include <hip/hip_bf16.h>
#include <math.h>

// CodecAttention: x->QKV proj (bf16 MFMA, V written transposed) -> RMSNorm(q,k)
// -> MFMA sliding-window ALiBi attention (win=16) -> out proj.
// B=4 T=2048 DIM=1024 H=8 D=128.

#define TSEQ 2048
#define DIMW 1024
#define NHEAD 8
#define WIN 16

typedef __bf16 bf16x8_t __attribute__((ext_vector_type(8)));
typedef float f32x4_t __attribute__((ext_vector_type(4)));

__device__ __forceinline__ unsigned short f2bf(float f) {
  unsigned u = __float_as_uint(f);
  u += 0x7fffu + ((u >> 16) & 1u);   // round-to-nearest-even
  return (unsigned short)(u >> 16);
}
__device__ __forceinline__ float bflo(unsigned u) { return __uint_as_float(u << 16); }
__device__ __forceinline__ float bfhi(unsigned u) { return __uint_as_float(u & 0xffff0000u); }

// ---------- f32 -> bf16 conversion of x ----------
__global__ __launch_bounds__(256)
void k_conv_x(const float* __restrict__ x, unsigned short* __restrict__ xb, int n4) {
  int i = blockIdx.x * 256 + threadIdx.x;
  if (i >= n4) return;
  float4 v = ((const float4*)x)[i];
  ushort4 o;
  o.x = f2bf(v.x); o.y = f2bf(v.y); o.z = f2bf(v.z); o.w = f2bf(v.w);
  ((ushort4*)xb)[i] = o;
}

// ---------- transpose + convert weights: Wt[z][n][k] = w_z[k][n] ----------
__global__ __launch_bounds__(256)
void k_conv_w(const float* __restrict__ wq, const float* __restrict__ wk,
              const float* __restrict__ wv, const float* __restrict__ wo,
              unsigned short* __restrict__ Wt) {
  __shared__ float tile[32][33];
  const int z = blockIdx.z;
  const float* src = (z == 0) ? wq : (z == 1) ? wk : (z == 2) ? wv : wo;
  const int n0 = blockIdx.x * 32;
  const int k0 = blockIdx.y * 32;
  const int tx = threadIdx.x, ty = threadIdx.y;  // 32 x 8
#pragma unroll
  for (int i = 0; i < 4; ++i)
    tile[ty + 8 * i][tx] = src[(size_t)(k0 + ty + 8 * i) * DIMW + n0 + tx];
  __syncthreads();
#pragma unroll
  for (int i = 0; i < 4; ++i)
    Wt[(size_t)z * DIMW * DIMW + (size_t)(n0 + ty + 8 * i) * DIMW + k0 + tx] =
        f2bf(tile[tx][ty + 8 * i]);
}

// ---------- bf16 TN GEMM, counted-vmcnt ring pipeline ----------
// Block tile 256(M) x 128(N), 512 threads = 8 waves (4x2) of 64x64.
// BK=32 chunks; 4-slot LDS ring (4 x 24KB = 96KB), prefetch distance 3.
// Per iter c: vmcnt(6) retires chunk c (c+1,c+2 stay in flight -- T4, never
// drain to 0); s_barrier makes the landing collective (each wave's own loads
// retired before ITS vmcnt; barrier => all waves' loads for chunk c landed);
// then STAGE(c+3) into slot (c-1)&3 -- every wave's ds_reads of that slot
// happened last iteration, before the lgkmcnt(0) preceding its MFMAs, hence
// before this barrier => no write-while-read. One barrier per chunk.
// Frag reads on [rows][64B] rows: bank-quad = (row*4 + kg) & 7 -> 8 quads x 8
// lanes = conflict-free, no swizzle needed.
// MODE 0: bf16 out; cols<2048 -> Cb[row][2048]; cols>=2048 (V third) written
//         TRANSPOSED into Vt[(b*8+h)*128+d][t].  MODE 1: f32 out Cf[row][N].
#define GLDS(gp, lp)                                                        \
  __builtin_amdgcn_global_load_lds(                                         \
      (const __attribute__((address_space(1))) void*)(gp),                  \
      (__attribute__((address_space(3))) void*)(lp), 16, 0, 0)

template <int MODE>
__global__ __launch_bounds__(512, 2)
void k_gemm(const unsigned short* __restrict__ A,   // [M][K] bf16
            const unsigned short* __restrict__ Bt,  // [N][K] bf16
            unsigned short* __restrict__ Cb,        // bf16 out (MODE 0, q|k part)
            unsigned short* __restrict__ Vt,        // bf16 out (MODE 0, v part, transposed)
            float* __restrict__ Cf,                 // f32 out  (MODE 1)
            int M, int N, int K) {
  __shared__ __align__(16) unsigned char smem[98304];  // 4 x (A 16KB + B 8KB)
  const int tid = threadIdx.x;
  const int lane = tid & 63;
  const int w = tid >> 6;          // wave 0..7
  const int wm = w >> 1, wn = w & 1;

  // XCD-aware bijective swizzle (grids are multiples of 8)
  const int nwg = gridDim.x * gridDim.y;
  int flat = blockIdx.y * gridDim.x + blockIdx.x;
  flat = (flat & 7) * (nwg >> 3) + (flat >> 3);
  const int bx = flat % gridDim.x;
  const int by = flat / gridDim.x;

  // Staging: per chunk, per thread: 2 A-loads + 1 B-load (16B each).
  // A issue i: LDS row = i*128 + w*16 + (lane>>2), colgrp = lane&3.
  const int r2 = lane >> 2;
  const int cg = (lane & 3) * 8;
  const size_t aS0 = (size_t)(by * 256 + w * 16 + r2) * K + cg;
  const size_t aS1 = aS0 + (size_t)128 * K;
  const size_t bS = (size_t)(bx * 128 + w * 16 + r2) * K + cg;
  const int dA0 = w * 1024;          // + lane*16 by HW
  const int dA1 = 8192 + w * 1024;
  const int dB = 16384 + w * 1024;

  // Fragment read offsets (within slot): A row wm*64+m*16+(lane&15), kg=lane>>4
  const int aRd = (wm * 64 + (lane & 15)) * 64 + (lane >> 4) * 16;
  const int bRd = 16384 + (wn * 64 + (lane & 15)) * 64 + (lane >> 4) * 16;

  f32x4_t acc[4][4];
#pragma unroll
  for (int m = 0; m < 4; ++m)
#pragma unroll
    for (int n = 0; n < 4; ++n) acc[m][n] = (f32x4_t){0.f, 0.f, 0.f, 0.f};

  const int nc = K >> 5;  // 32
  // prologue: stage chunks 0,1,2 (9 loads/thread in flight)
#pragma unroll
  for (int c = 0; c < 3; ++c) {
    unsigned char* s = smem + (c & 3) * 24576;
    GLDS(A + aS0 + c * 32, s + dA0);
    GLDS(A + aS1 + c * 32, s + dA1);
    GLDS(Bt + bS + c * 32, s + dB);
  }
#pragma unroll 1
  for (int c = 0; c < nc; ++c) {
    if (c + 2 < nc)      asm volatile("s_waitcnt vmcnt(6)" ::: "memory");
    else if (c + 1 < nc) asm volatile("s_waitcnt vmcnt(3)" ::: "memory");
    else                 asm volatile("s_waitcnt vmcnt(0)" ::: "memory");
    __builtin_amdgcn_s_barrier();
    unsigned char* s = smem + (c & 3) * 24576;
    if (c + 3 < nc) {
      unsigned char* sn = smem + ((c + 3) & 3) * 24576;
      GLDS(A + aS0 + (c + 3) * 32, sn + dA0);
      GLDS(A + aS1 + (c + 3) * 32, sn + dA1);
      GLDS(Bt + bS + (c + 3) * 32, sn + dB);
    }
    bf16x8_t af[4], bfr[4];
#pragma unroll
    for (int m = 0; m < 4; ++m) af[m] = *(const bf16x8_t*)(s + aRd + m * 1024);
#pragma unroll
    for (int n = 0; n < 4; ++n) bfr[n] = *(const bf16x8_t*)(s + bRd + n * 1024);
    __builtin_amdgcn_s_setprio(1);
#pragma unroll
    for (int m = 0; m < 4; ++m)
#pragma unroll
      for (int n = 0; n < 4; ++n)
        acc[m][n] = __builtin_amdgcn_mfma_f32_16x16x32_bf16(af[m], bfr[n], acc[m][n], 0, 0, 0);
    __builtin_amdgcn_s_setprio(0);
  }

  // C/D layout (m89-verified): col = lane&15, row = (lane>>4)*4 + reg
  const int row0 = by * 256 + wm * 64 + ((lane >> 4) << 2);
  const int col0 = bx * 128 + wn * 64 + (lane & 15);
#pragma unroll
  for (int m = 0; m < 4; ++m)
#pragma unroll
    for (int n = 0; n < 4; ++n)
#pragma unroll
      for (int r = 0; r < 4; ++r) {
        const int row = row0 + m * 16 + r;
        const int col = col0 + n * 16;
        const float v = acc[m][n][r];
        if (MODE == 1) {
          Cf[(size_t)row * N + col] = v;
        } else if (col < 2048) {
          Cb[(size_t)row * 2048 + col] = f2bf(v);
        } else {
          const int vcol = col - 2048;
          const int hh = vcol >> 7, dd = vcol & 127;
          const int bb = row >> 11, tt = row & 2047;
          Vt[((size_t)(bb * NHEAD + hh) * 128 + dd) * TSEQ + tt] = f2bf(v);
        }
      }
}

// ---------- in-place RMSNorm on q (cols 0..1023) and k (cols 1024..2047) ----------
__global__ __launch_bounds__(256)
void k_rmsnorm(unsigned short* __restrict__ qk, const float* __restrict__ qw,
               const float* __restrict__ kw) {
  const int row = blockIdx.x;
  const int tid = threadIdx.x;
  unsigned short* base = qk + (size_t)row * 2048;
  uint2 uq = *(const uint2*)(base + tid * 4);
  uint2 uk = *(const uint2*)(base + 1024 + tid * 4);
  float q0 = bflo(uq.x), q1 = bfhi(uq.x), q2 = bflo(uq.y), q3 = bfhi(uq.y);
  float k0 = bflo(uk.x), k1 = bfhi(uk.x), k2 = bflo(uk.y), k3 = bfhi(uk.y);
  float sq = q0 * q0 + q1 * q1 + q2 * q2 + q3 * q3;
  float sk = k0 * k0 + k1 * k1 + k2 * k2 + k3 * k3;
#pragma unroll
  for (int off = 32; off > 0; off >>= 1) {
    sq += __shfl_xor(sq, off);
    sk += __shfl_xor(sk, off);
  }
  __shared__ float red[8];
  const int w = tid >> 6;
  if ((tid & 63) == 0) { red[w] = sq; red[4 + w] = sk; }
  __syncthreads();
  sq = red[0] + red[1] + red[2] + red[3];
  sk = red[4] + red[5] + red[6] + red[7];
  const float rq = rsqrtf(sq * (1.0f / 1024.0f) + 1e-6f);
  const float rk = rsqrtf(sk * (1.0f / 1024.0f) + 1e-6f);
  const int c = tid * 4;
  uint2 oq, ok;
  oq.x = (unsigned)f2bf(q0 * rq * qw[c]) | ((unsigned)f2bf(q1 * rq * qw[c + 1]) << 16);
  oq.y = (unsigned)f2bf(q2 * rq * qw[c + 2]) | ((unsigned)f2bf(q3 * rq * qw[c + 3]) << 16);
  ok.x = (unsigned)f2bf(k0 * rk * kw[c]) | ((unsigned)f2bf(k1 * rk * kw[c + 1]) << 16);
  ok.y = (unsigned)f2bf(k2 * rk * kw[c + 2]) | ((unsigned)f2bf(k3 * rk * kw[c + 3]) << 16);
  *(uint2*)(base + tid * 4) = oq;
  *(uint2*)(base + 1024 + tid * 4) = ok;
}

// ---------- MFMA sliding-window ALiBi attention ----------
// One wave per 16 queries of one (b,h). Key window: 32 keys [t0-16, t0+16).
// Swapped QK^T (A=K, B=Q) -> S^T: lane holds query c=lane&15, keys g*4+r (+16).
// Softmax: in-lane over 8 + shfl_xor(16,32). P -> padded LDS -> A-frag for PV.
// V read from transposed Vt buffer as b128 B-frags.
__global__ __launch_bounds__(256)
void k_attn(const unsigned short* __restrict__ qk,   // [8192][2048] q|k (normalized)
            const unsigned short* __restrict__ vt,   // [(b*8+h)*128+d][2048]
            unsigned short* __restrict__ outb) {     // [8192][1024] bf16
  __shared__ __align__(16) unsigned char plds_all[4][1280];  // 16 rows x 80B (40 elems)
  const int lane = threadIdx.x & 63;
  const int wv = threadIdx.x >> 6;
  unsigned char* plds = plds_all[wv];
  const int bh = blockIdx.y;                 // 0..31
  const int b = bh >> 3, h = bh & 7;
  const int t0 = blockIdx.x * 64 + wv * 16;
  const int g = lane >> 4, c = lane & 15;
  const int jlo = t0 - 16;

  // Q B-fragments: Q[t0+c][kc*32 + g*8 .. +8]
  const unsigned short* qrow = qk + (size_t)(b * TSEQ + t0 + c) * 2048 + h * 128 + g * 8;
  bf16x8_t qf[4];
#pragma unroll
  for (int kc = 0; kc < 4; ++kc) qf[kc] = *(const bf16x8_t*)(qrow + kc * 32);

  // K A-fragments (2 key-tiles); clamp negative rows (masked anyway)
  const int j0 = jlo + c;
  const int j0c = (j0 < 0) ? 0 : j0;
  const unsigned short* krow0 = qk + (size_t)(b * TSEQ + j0c) * 2048 + 1024 + h * 128 + g * 8;
  const unsigned short* krow1 = qk + (size_t)(b * TSEQ + t0 + c) * 2048 + 1024 + h * 128 + g * 8;
  bf16x8_t kf0[4], kf1[4];
#pragma unroll
  for (int kc = 0; kc < 4; ++kc) {
    kf0[kc] = *(const bf16x8_t*)(krow0 + kc * 32);
    kf1[kc] = *(const bf16x8_t*)(krow1 + kc * 32);
  }

  f32x4_t s0 = (f32x4_t){0.f, 0.f, 0.f, 0.f};
  f32x4_t s1 = (f32x4_t){0.f, 0.f, 0.f, 0.f};
#pragma unroll
  for (int kc = 0; kc < 4; ++kc) {
    s0 = __builtin_amdgcn_mfma_f32_16x16x32_bf16(kf0[kc], qf[kc], s0, 0, 0, 0);
    s1 = __builtin_amdgcn_mfma_f32_16x16x32_bf16(kf1[kc], qf[kc], s1, 0, 0, 0);
  }

  // scores + mask + bias. key kk = z*16 + g*4 + r; query = c; rel = kk-16-c.
  const float scale = 0.08838834764831845f;  // 1/sqrt(128)
  const float slope = 1.0f / (float)(1 << h);
  float val[8];
#pragma unroll
  for (int z = 0; z < 2; ++z)
#pragma unroll
    for (int r = 0; r < 4; ++r) {
      const int kk = z * 16 + g * 4 + r;
      const int rel = kk - 16 - c;
      const bool ok = (rel <= 0) & (rel >= -WIN) & (jlo + kk >= 0);
      const float sc = (z == 0) ? s0[r] : s1[r];
      val[z * 4 + r] = ok ? (sc * scale + slope * (float)rel) : -1.0e30f;
    }
  float m = val[0];
#pragma unroll
  for (int i = 1; i < 8; ++i) m = fmaxf(m, val[i]);
  m = fmaxf(m, __shfl_xor(m, 16));
  m = fmaxf(m, __shfl_xor(m, 32));
  float e[8], s = 0.f;
#pragma unroll
  for (int i = 0; i < 8; ++i) { e[i] = __expf(val[i] - m); s += e[i]; }
  s += __shfl_xor(s, 16);
  s += __shfl_xor(s, 32);
  const float inv = 1.0f / s;

  // P -> LDS [query c][key kk], row stride 40 elems (80B): 2-way banks = free
#pragma unroll
  for (int z = 0; z < 2; ++z) {
    uint2 pk;
    pk.x = (unsigned)f2bf(e[z * 4 + 0] * inv) | ((unsigned)f2bf(e[z * 4 + 1] * inv) << 16);
    pk.y = (unsigned)f2bf(e[z * 4 + 2] * inv) | ((unsigned)f2bf(e[z * 4 + 3] * inv) << 16);
    *(uint2*)(plds + c * 80 + z * 32 + g * 8) = pk;
  }
  // A-fragment of P: row=c (query), keys g*8..+8
  const bf16x8_t pf = *(const bf16x8_t*)(plds + c * 80 + g * 16);

  // PV: B-frag = V[jlo + g*8 + i][d0 + c] = Vt[d0+c][jlo + g*8 ...]
  const int vc0 = jlo + g * 8;
  const int vcc = (vc0 < 0) ? 0 : vc0;   // garbage rows get zero weight
  const unsigned short* vbase = vt + (size_t)(bh * 128 + c) * TSEQ + vcc;
  unsigned short* orow = outb + (size_t)(b * TSEQ + t0) * 1024 + h * 128 + c;
#pragma unroll
  for (int n = 0; n < 8; ++n) {
    const bf16x8_t vf = *(const bf16x8_t*)(vbase + (size_t)n * 16 * TSEQ);
    f32x4_t o = __builtin_amdgcn_mfma_f32_16x16x32_bf16(pf, vf, (f32x4_t){0.f, 0.f, 0.f, 0.f},
                                                        0, 0, 0);
    // C: row=(g*4+r)=query, col=c=d within chunk n
#pragma unroll
    for (int r = 0; r < 4; ++r)
      orow[(size_t)(g * 4 + r) * 1024 + n * 16] = f2bf(o[r]);
  }
}

extern "C" void kernel_launch(void* const* d_in, const int* in_sizes, int n_in,
                              void* d_out, int out_size, void* d_ws, size_t ws_size,
                              hipStream_t stream) {
  const float* x = (const float*)d_in[0];
  const float* wq = (const float*)d_in[1];
  const float* wk = (const float*)d_in[2];
  const float* wv = (const float*)d_in[3];
  const float* wo = (const float*)d_in[4];
  const float* qnw = (const float*)d_in[5];
  const float* knw = (const float*)d_in[6];
  float* out = (float*)d_out;

  const int M = 4 * TSEQ;  // 8192 rows
  // workspace (75.5 MB):
  //   xb  [M][1024] bf16 (16.8 MB)  -- x bf16; later reused as attention output
  //   Wt  [4][1024][1024] bf16 (8.4 MB)
  //   qk  [M][2048] bf16 (33.5 MB)  -- q|k (normalized in place)
  //   Vt  [32][128][2048] bf16 (16.8 MB) -- V transposed per (b,h)
  unsigned short* xb = (unsigned short*)d_ws;
  unsigned short* Wt = xb + (size_t)M * DIMW;
  unsigned short* qkb = Wt + (size_t)4 * DIMW * DIMW;
  unsigned short* Vt = qkb + (size_t)M * 2048;
  if (ws_size < ((size_t)M * DIMW + (size_t)4 * DIMW * DIMW + (size_t)M * 2048 +
                 (size_t)M * 2048) * 2) return;

  k_conv_x<<<(M * DIMW / 4 + 255) / 256, 256, 0, stream>>>(x, xb, M * DIMW / 4);
  k_conv_w<<<dim3(32, 32, 4), dim3(32, 8), 0, stream>>>(wq, wk, wv, wo, Wt);
  k_gemm<0><<<dim3(24, 32), 512, 0, stream>>>(xb, Wt, qkb, Vt, nullptr, M, 3072, 1024);
  k_rmsnorm<<<M, 256, 0, stream>>>(qkb, qnw, knw);
  k_attn<<<dim3(TSEQ / 64, 32), 256, 0, stream>>>(qkb, Vt, xb);  // xb = attn out
  k_gemm<1><<<dim3(8, 32), 512, 0, stream>>>(xb, Wt + (size_t)3 * DIMW * DIMW, nullptr,
                                             nullptr, out, M, 1024, 1024);
}

// Round 4
// 235.642 us; speedup vs baseline: 1.4617x; 1.0229x over previous
//
#include <hip/hip_runtime.h>
#include <hip/hip_bf16.h>
#include <math.h>

// CodecAttention: x->QKV proj (bf16 MFMA, V written transposed) -> RMSNorm(q,k)
// -> MFMA sliding-window ALiBi attention (win=16) -> out proj.
// B=4 T=2048 DIM=1024 H=8 D=128.

#define TSEQ 2048
#define DIMW 1024
#define NHEAD 8
#define WIN 16

typedef __bf16 bf16x8_t __attribute__((ext_vector_type(8)));
typedef float f32x4_t __attribute__((ext_vector_type(4)));

__device__ __forceinline__ unsigned short f2bf(float f) {
  unsigned u = __float_as_uint(f);
  u += 0x7fffu + ((u >> 16) & 1u);   // round-to-nearest-even
  return (unsigned short)(u >> 16);
}
__device__ __forceinline__ float bflo(unsigned u) { return __uint_as_float(u << 16); }
__device__ __forceinline__ float bfhi(unsigned u) { return __uint_as_float(u & 0xffff0000u); }

// ---------- f32 -> bf16 conversion of x ----------
__global__ __launch_bounds__(256)
void k_conv_x(const float* __restrict__ x, unsigned short* __restrict__ xb, int n4) {
  int i = blockIdx.x * 256 + threadIdx.x;
  if (i >= n4) return;
  float4 v = ((const float4*)x)[i];
  ushort4 o;
  o.x = f2bf(v.x); o.y = f2bf(v.y); o.z = f2bf(v.z); o.w = f2bf(v.w);
  ((ushort4*)xb)[i] = o;
}

// ---------- transpose + convert weights: Wt[z][n][k] = w_z[k][n] ----------
__global__ __launch_bounds__(256)
void k_conv_w(const float* __restrict__ wq, const float* __restrict__ wk,
              const float* __restrict__ wv, const float* __restrict__ wo,
              unsigned short* __restrict__ Wt) {
  __shared__ float tile[32][33];
  const int z = blockIdx.z;
  const float* src = (z == 0) ? wq : (z == 1) ? wk : (z == 2) ? wv : wo;
  const int n0 = blockIdx.x * 32;
  const int k0 = blockIdx.y * 32;
  const int tx = threadIdx.x, ty = threadIdx.y;  // 32 x 8
#pragma unroll
  for (int i = 0; i < 4; ++i)
    tile[ty + 8 * i][tx] = src[(size_t)(k0 + ty + 8 * i) * DIMW + n0 + tx];
  __syncthreads();
#pragma unroll
  for (int i = 0; i < 4; ++i)
    Wt[(size_t)z * DIMW * DIMW + (size_t)(n0 + ty + 8 * i) * DIMW + k0 + tx] =
        f2bf(tile[tx][ty + 8 * i]);
}

// ---------- bf16 TN GEMM, counted-vmcnt ring pipeline ----------
// Block tile 256(M) x 128(N), 512 threads = 8 waves (4x2) of 64x64.
// BK=32 chunks; 4-slot LDS ring (4 x 24KB = 96KB), prefetch distance 3.
// Per iter c: vmcnt(6) retires chunk c (c+1,c+2 stay in flight -- T4, never
// drain to 0); s_barrier makes the landing collective; then STAGE(c+3) into
// slot (c-1)&3 (its readers all passed the previous lgkmcnt+barrier).
// One barrier per chunk.
// XOR swizzle (rule 21, both-sides, R2-verified 0 conflicts): LDS slot
// (row, g) holds global k-group kg = g ^ ((row>>1)&3). Staging pre-swizzles
// the GLOBAL source (LDS dest stays linear for global_load_lds); frag reads
// apply the same involution -> bank-quads {0,4,1,5,2,6,3,7}x2 = 2-way = free.
// MODE 0: bf16 out; cols<2048 -> Cb[row][2048]; cols>=2048 (V third) written
//         TRANSPOSED into Vt[(b*8+h)*128+d][t].  MODE 1: f32 out Cf[row][N].
#define GLDS(gp, lp)                                                        \
  __builtin_amdgcn_global_load_lds(                                         \
      (const __attribute__((address_space(1))) void*)(gp),                  \
      (__attribute__((address_space(3))) void*)(lp), 16, 0, 0)

template <int MODE>
__global__ __launch_bounds__(512, 2)
void k_gemm(const unsigned short* __restrict__ A,   // [M][K] bf16
            const unsigned short* __restrict__ Bt,  // [N][K] bf16
            unsigned short* __restrict__ Cb,        // bf16 out (MODE 0, q|k part)
            unsigned short* __restrict__ Vt,        // bf16 out (MODE 0, v part, transposed)
            float* __restrict__ Cf,                 // f32 out  (MODE 1)
            int M, int N, int K) {
  __shared__ __align__(16) unsigned char smem[98304];  // 4 x (A 16KB + B 8KB)
  const int tid = threadIdx.x;
  const int lane = tid & 63;
  const int w = tid >> 6;          // wave 0..7
  const int wm = w >> 1, wn = w & 1;

  // XCD-aware bijective swizzle (grids are multiples of 8)
  const int nwg = gridDim.x * gridDim.y;
  int flat = blockIdx.y * gridDim.x + blockIdx.x;
  flat = (flat & 7) * (nwg >> 3) + (flat >> 3);
  const int bx = flat % gridDim.x;
  const int by = flat / gridDim.x;

  // Staging: per chunk, per thread: 2 A-loads + 1 B-load (16B each).
  // LDS row = issue_base + w*16 + (lane>>2), slot g = lane&3; global source
  // k-group pre-swizzled: kg = g ^ ((row>>1)&3) = (lane&3) ^ ((lane>>3)&3)
  // (w*16 and +128 contribute 0 mod 8 to row).
  const int r2 = lane >> 2;
  const int cg = ((lane & 3) ^ ((lane >> 3) & 3)) * 8;  // elements
  const size_t aS0 = (size_t)(by * 256 + w * 16 + r2) * K + cg;
  const size_t aS1 = aS0 + (size_t)128 * K;
  const size_t bS = (size_t)(bx * 128 + w * 16 + r2) * K + cg;
  const int dA0 = w * 1024;          // + lane*16 by HW
  const int dA1 = 8192 + w * 1024;
  const int dB = 16384 + w * 1024;

  // Fragment reads: row = w?*64 + m*16 + (lane&15), kg = lane>>4;
  // slot g = kg ^ ((row>>1)&3) = (lane>>4) ^ ((lane>>1)&3).
  const int swz = ((lane >> 4) ^ ((lane >> 1) & 3)) * 16;
  const int aRd = (wm * 64 + (lane & 15)) * 64 + swz;
  const int bRd = 16384 + (wn * 64 + (lane & 15)) * 64 + swz;

  f32x4_t acc[4][4];
#pragma unroll
  for (int m = 0; m < 4; ++m)
#pragma unroll
    for (int n = 0; n < 4; ++n) acc[m][n] = (f32x4_t){0.f, 0.f, 0.f, 0.f};

  const int nc = K >> 5;  // 32
  // prologue: stage chunks 0,1,2 (9 loads/thread in flight)
#pragma unroll
  for (int c = 0; c < 3; ++c) {
    unsigned char* s = smem + (c & 3) * 24576;
    GLDS(A + aS0 + c * 32, s + dA0);
    GLDS(A + aS1 + c * 32, s + dA1);
    GLDS(Bt + bS + c * 32, s + dB);
  }
#pragma unroll 1
  for (int c = 0; c < nc; ++c) {
    if (c + 2 < nc)      asm volatile("s_waitcnt vmcnt(6)" ::: "memory");
    else if (c + 1 < nc) asm volatile("s_waitcnt vmcnt(3)" ::: "memory");
    else                 asm volatile("s_waitcnt vmcnt(0)" ::: "memory");
    __builtin_amdgcn_s_barrier();
    unsigned char* s = smem + (c & 3) * 24576;
    if (c + 3 < nc) {
      unsigned char* sn = smem + ((c + 3) & 3) * 24576;
      GLDS(A + aS0 + (c + 3) * 32, sn + dA0);
      GLDS(A + aS1 + (c + 3) * 32, sn + dA1);
      GLDS(Bt + bS + (c + 3) * 32, sn + dB);
    }
    bf16x8_t af[4], bfr[4];
#pragma unroll
    for (int m = 0; m < 4; ++m) af[m] = *(const bf16x8_t*)(s + aRd + m * 1024);
#pragma unroll
    for (int n = 0; n < 4; ++n) bfr[n] = *(const bf16x8_t*)(s + bRd + n * 1024);
    __builtin_amdgcn_s_setprio(1);
#pragma unroll
    for (int m = 0; m < 4; ++m)
#pragma unroll
      for (int n = 0; n < 4; ++n)
        acc[m][n] = __builtin_amdgcn_mfma_f32_16x16x32_bf16(af[m], bfr[n], acc[m][n], 0, 0, 0);
    __builtin_amdgcn_s_setprio(0);
  }

  // C/D layout (m89-verified): col = lane&15, row = (lane>>4)*4 + reg
  const int row0 = by * 256 + wm * 64 + ((lane >> 4) << 2);
  const int col0 = bx * 128 + wn * 64 + (lane & 15);
#pragma unroll
  for (int m = 0; m < 4; ++m)
#pragma unroll
    for (int n = 0; n < 4; ++n)
#pragma unroll
      for (int r = 0; r < 4; ++r) {
        const int row = row0 + m * 16 + r;
        const int col = col0 + n * 16;
        const float v = acc[m][n][r];
        if (MODE == 1) {
          Cf[(size_t)row * N + col] = v;
        } else if (col < 2048) {
          Cb[(size_t)row * 2048 + col] = f2bf(v);
        } else {
          const int vcol = col - 2048;
          const int hh = vcol >> 7, dd = vcol & 127;
          const int bb = row >> 11, tt = row & 2047;
          Vt[((size_t)(bb * NHEAD + hh) * 128 + dd) * TSEQ + tt] = f2bf(v);
        }
      }
}

// ---------- in-place RMSNorm on q (cols 0..1023) and k (cols 1024..2047) ----------
__global__ __launch_bounds__(256)
void k_rmsnorm(unsigned short* __restrict__ qk, const float* __restrict__ qw,
               const float* __restrict__ kw) {
  const int row = blockIdx.x;
  const int tid = threadIdx.x;
  unsigned short* base = qk + (size_t)row * 2048;
  uint2 uq = *(const uint2*)(base + tid * 4);
  uint2 uk = *(const uint2*)(base + 1024 + tid * 4);
  float q0 = bflo(uq.x), q1 = bfhi(uq.x), q2 = bflo(uq.y), q3 = bfhi(uq.y);
  float k0 = bflo(uk.x), k1 = bfhi(uk.x), k2 = bflo(uk.y), k3 = bfhi(uk.y);
  float sq = q0 * q0 + q1 * q1 + q2 * q2 + q3 * q3;
  float sk = k0 * k0 + k1 * k1 + k2 * k2 + k3 * k3;
#pragma unroll
  for (int off = 32; off > 0; off >>= 1) {
    sq += __shfl_xor(sq, off);
    sk += __shfl_xor(sk, off);
  }
  __shared__ float red[8];
  const int w = tid >> 6;
  if ((tid & 63) == 0) { red[w] = sq; red[4 + w] = sk; }
  __syncthreads();
  sq = red[0] + red[1] + red[2] + red[3];
  sk = red[4] + red[5] + red[6] + red[7];
  const float rq = rsqrtf(sq * (1.0f / 1024.0f) + 1e-6f);
  const float rk = rsqrtf(sk * (1.0f / 1024.0f) + 1e-6f);
  const int c = tid * 4;
  uint2 oq, ok;
  oq.x = (unsigned)f2bf(q0 * rq * qw[c]) | ((unsigned)f2bf(q1 * rq * qw[c + 1]) << 16);
  oq.y = (unsigned)f2bf(q2 * rq * qw[c + 2]) | ((unsigned)f2bf(q3 * rq * qw[c + 3]) << 16);
  ok.x = (unsigned)f2bf(k0 * rk * kw[c]) | ((unsigned)f2bf(k1 * rk * kw[c + 1]) << 16);
  ok.y = (unsigned)f2bf(k2 * rk * kw[c + 2]) | ((unsigned)f2bf(k3 * rk * kw[c + 3]) << 16);
  *(uint2*)(base + tid * 4) = oq;
  *(uint2*)(base + 1024 + tid * 4) = ok;
}

// ---------- MFMA sliding-window ALiBi attention ----------
// One wave per 16 queries of one (b,h). Key window: 32 keys [t0-16, t0+16).
// Swapped QK^T (A=K, B=Q) -> S^T: lane holds query c=lane&15, keys g*4+r (+16).
// Softmax: in-lane over 8 + shfl_xor(16,32). P -> padded LDS -> A-frag for PV.
// V read from transposed Vt buffer as b128 B-frags.
__global__ __launch_bounds__(256)
void k_attn(const unsigned short* __restrict__ qk,   // [8192][2048] q|k (normalized)
            const unsigned short* __restrict__ vt,   // [(b*8+h)*128+d][2048]
            unsigned short* __restrict__ outb) {     // [8192][1024] bf16
  __shared__ __align__(16) unsigned char plds_all[4][1280];  // 16 rows x 80B (40 elems)
  const int lane = threadIdx.x & 63;
  const int wv = threadIdx.x >> 6;
  unsigned char* plds = plds_all[wv];
  const int bh = blockIdx.y;                 // 0..31
  const int b = bh >> 3, h = bh & 7;
  const int t0 = blockIdx.x * 64 + wv * 16;
  const int g = lane >> 4, c = lane & 15;
  const int jlo = t0 - 16;

  // Q B-fragments: Q[t0+c][kc*32 + g*8 .. +8]
  const unsigned short* qrow = qk + (size_t)(b * TSEQ + t0 + c) * 2048 + h * 128 + g * 8;
  bf16x8_t qf[4];
#pragma unroll
  for (int kc = 0; kc < 4; ++kc) qf[kc] = *(const bf16x8_t*)(qrow + kc * 32);

  // K A-fragments (2 key-tiles); clamp negative rows (masked anyway)
  const int j0 = jlo + c;
  const int j0c = (j0 < 0) ? 0 : j0;
  const unsigned short* krow0 = qk + (size_t)(b * TSEQ + j0c) * 2048 + 1024 + h * 128 + g * 8;
  const unsigned short* krow1 = qk + (size_t)(b * TSEQ + t0 + c) * 2048 + 1024 + h * 128 + g * 8;
  bf16x8_t kf0[4], kf1[4];
#pragma unroll
  for (int kc = 0; kc < 4; ++kc) {
    kf0[kc] = *(const bf16x8_t*)(krow0 + kc * 32);
    kf1[kc] = *(const bf16x8_t*)(krow1 + kc * 32);
  }

  f32x4_t s0 = (f32x4_t){0.f, 0.f, 0.f, 0.f};
  f32x4_t s1 = (f32x4_t){0.f, 0.f, 0.f, 0.f};
#pragma unroll
  for (int kc = 0; kc < 4; ++kc) {
    s0 = __builtin_amdgcn_mfma_f32_16x16x32_bf16(kf0[kc], qf[kc], s0, 0, 0, 0);
    s1 = __builtin_amdgcn_mfma_f32_16x16x32_bf16(kf1[kc], qf[kc], s1, 0, 0, 0);
  }

  // scores + mask + bias. key kk = z*16 + g*4 + r; query = c; rel = kk-16-c.
  const float scale = 0.08838834764831845f;  // 1/sqrt(128)
  const float slope = 1.0f / (float)(1 << h);
  float val[8];
#pragma unroll
  for (int z = 0; z < 2; ++z)
#pragma unroll
    for (int r = 0; r < 4; ++r) {
      const int kk = z * 16 + g * 4 + r;
      const int rel = kk - 16 - c;
      const bool ok = (rel <= 0) & (rel >= -WIN) & (jlo + kk >= 0);
      const float sc = (z == 0) ? s0[r] : s1[r];
      val[z * 4 + r] = ok ? (sc * scale + slope * (float)rel) : -1.0e30f;
    }
  float m = val[0];
#pragma unroll
  for (int i = 1; i < 8; ++i) m = fmaxf(m, val[i]);
  m = fmaxf(m, __shfl_xor(m, 16));
  m = fmaxf(m, __shfl_xor(m, 32));
  float e[8], s = 0.f;
#pragma unroll
  for (int i = 0; i < 8; ++i) { e[i] = __expf(val[i] - m); s += e[i]; }
  s += __shfl_xor(s, 16);
  s += __shfl_xor(s, 32);
  const float inv = 1.0f / s;

  // P -> LDS [query c][key kk], row stride 40 elems (80B): 2-way banks = free
#pragma unroll
  for (int z = 0; z < 2; ++z) {
    uint2 pk;
    pk.x = (unsigned)f2bf(e[z * 4 + 0] * inv) | ((unsigned)f2bf(e[z * 4 + 1] * inv) << 16);
    pk.y = (unsigned)f2bf(e[z * 4 + 2] * inv) | ((unsigned)f2bf(e[z * 4 + 3] * inv) << 16);
    *(uint2*)(plds + c * 80 + z * 32 + g * 8) = pk;
  }
  // A-fragment of P: row=c (query), keys g*8..+8
  const bf16x8_t pf = *(const bf16x8_t*)(plds + c * 80 + g * 16);

  // PV: B-frag = V[jlo + g*8 + i][d0 + c] = Vt[d0+c][jlo + g*8 ...]
  const int vc0 = jlo + g * 8;
  const int vcc = (vc0 < 0) ? 0 : vc0;   // garbage rows get zero weight
  const unsigned short* vbase = vt + (size_t)(bh * 128 + c) * TSEQ + vcc;
  unsigned short* orow = outb + (size_t)(b * TSEQ + t0) * 1024 + h * 128 + c;
#pragma unroll
  for (int n = 0; n < 8; ++n) {
    const bf16x8_t vf = *(const bf16x8_t*)(vbase + (size_t)n * 16 * TSEQ);
    f32x4_t o = __builtin_amdgcn_mfma_f32_16x16x32_bf16(pf, vf, (f32x4_t){0.f, 0.f, 0.f, 0.f},
                                                        0, 0, 0);
    // C: row=(g*4+r)=query, col=c=d within chunk n
#pragma unroll
    for (int r = 0; r < 4; ++r)
      orow[(size_t)(g * 4 + r) * 1024 + n * 16] = f2bf(o[r]);
  }
}

extern "C" void kernel_launch(void* const* d_in, const int* in_sizes, int n_in,
                              void* d_out, int out_size, void* d_ws, size_t ws_size,
                              hipStream_t stream) {
  const float* x = (const float*)d_in[0];
  const float* wq = (const float*)d_in[1];
  const float* wk = (const float*)d_in[2];
  const float* wv = (const float*)d_in[3];
  const float* wo = (const float*)d_in[4];
  const float* qnw = (const float*)d_in[5];
  const float* knw = (const float*)d_in[6];
  float* out = (float*)d_out;

  const int M = 4 * TSEQ;  // 8192 rows
  // workspace (75.5 MB):
  //   xb  [M][1024] bf16 (16.8 MB)  -- x bf16; later reused as attention output
  //   Wt  [4][1024][1024] bf16 (8.4 MB)
  //   qk  [M][2048] bf16 (33.5 MB)  -- q|k (normalized in place)
  //   Vt  [32][128][2048] bf16 (16.8 MB) -- V transposed per (b,h)
  unsigned short* xb = (unsigned short*)d_ws;
  unsigned short* Wt = xb + (size_t)M * DIMW;
  unsigned short* qkb = Wt + (size_t)4 * DIMW * DIMW;
  unsigned short* Vt = qkb + (size_t)M * 2048;
  if (ws_size < ((size_t)M * DIMW + (size_t)4 * DIMW * DIMW + (size_t)M * 2048 +
                 (size_t)M * 2048) * 2) return;

  k_conv_x<<<(M * DIMW / 4 + 255) / 256, 256, 0, stream>>>(x, xb, M * DIMW / 4);
  k_conv_w<<<dim3(32, 32, 4), dim3(32, 8), 0, stream>>>(wq, wk, wv, wo, Wt);
  k_gemm<0><<<dim3(24, 32), 512, 0, stream>>>(xb, Wt, qkb, Vt, nullptr, M, 3072, 1024);
  k_rmsnorm<<<M, 256, 0, stream>>>(qkb, qnw, knw);
  k_attn<<<dim3(TSEQ / 64, 32), 256, 0, stream>>>(qkb, Vt, xb);  // xb = attn out
  k_gemm<1><<<dim3(8, 32), 512, 0, stream>>>(xb, Wt + (size_t)3 * DIMW * DIMW, nullptr,
                                             nullptr, out, M, 1024, 1024);
}

// Round 5
// 216.487 us; speedup vs baseline: 1.5911x; 1.0885x over previous
//
#include <hip/hip_runtime.h>
#include <hip/hip_bf16.h>
#include <math.h>

// CodecAttention: x->QKV proj (bf16 MFMA, V written transposed) -> RMSNorm(q,k)
// -> MFMA sliding-window ALiBi attention (win=16) -> out proj.
// B=4 T=2048 DIM=1024 H=8 D=128.

#define TSEQ 2048
#define DIMW 1024
#define NHEAD 8
#define WIN 16

typedef __bf16 bf16x8_t __attribute__((ext_vector_type(8)));
typedef float f32x4_t __attribute__((ext_vector_type(4)));

__device__ __forceinline__ unsigned short f2bf(float f) {
  unsigned u = __float_as_uint(f);
  u += 0x7fffu + ((u >> 16) & 1u);   // round-to-nearest-even
  return (unsigned short)(u >> 16);
}
__device__ __forceinline__ float bflo(unsigned u) { return __uint_as_float(u << 16); }
__device__ __forceinline__ float bfhi(unsigned u) { return __uint_as_float(u & 0xffff0000u); }

// ---------- f32 -> bf16 conversion of x ----------
__global__ __launch_bounds__(256)
void k_conv_x(const float* __restrict__ x, unsigned short* __restrict__ xb, int n4) {
  int i = blockIdx.x * 256 + threadIdx.x;
  if (i >= n4) return;
  float4 v = ((const float4*)x)[i];
  ushort4 o;
  o.x = f2bf(v.x); o.y = f2bf(v.y); o.z = f2bf(v.z); o.w = f2bf(v.w);
  ((ushort4*)xb)[i] = o;
}

// ---------- transpose + convert weights: Wt[z][n][k] = w_z[k][n] ----------
__global__ __launch_bounds__(256)
void k_conv_w(const float* __restrict__ wq, const float* __restrict__ wk,
              const float* __restrict__ wv, const float* __restrict__ wo,
              unsigned short* __restrict__ Wt) {
  __shared__ float tile[32][33];
  const int z = blockIdx.z;
  const float* src = (z == 0) ? wq : (z == 1) ? wk : (z == 2) ? wv : wo;
  const int n0 = blockIdx.x * 32;
  const int k0 = blockIdx.y * 32;
  const int tx = threadIdx.x, ty = threadIdx.y;  // 32 x 8
#pragma unroll
  for (int i = 0; i < 4; ++i)
    tile[ty + 8 * i][tx] = src[(size_t)(k0 + ty + 8 * i) * DIMW + n0 + tx];
  __syncthreads();
#pragma unroll
  for (int i = 0; i < 4; ++i)
    Wt[(size_t)z * DIMW * DIMW + (size_t)(n0 + ty + 8 * i) * DIMW + k0 + tx] =
        f2bf(tile[tx][ty + 8 * i]);
}

// ---------- bf16 TN GEMM, 8-phase (4 sub-phases / K-tile) pipeline ----------
// Block tile 256(M) x BN, 512 threads = 8 waves (2 rows x 4 cols), wave tile
// 128 x BN/4.  BK=64 (2 k-slices of 32); double-buffered LDS:
//   buf p: A [2 slices][256 rows][64B]  (32KB)  +  B [2][BN][64B] (BN*128 B)
// Staging: global_load_lds width 16, source col-group pre-swizzled with the
// involution kg = g ^ ((row>>1)&3) (R4-verified: SQ_LDS_BANK_CONFLICT == 0);
// fragment ds_read_b128 applies the same involution.
// Ledger (BN=256; 8 loads/wave/K-tile, issue order = consumption order
// [As0h0,Bs0h0,Bs0h1,As0h1, As1h0,Bs1h0,Bs1h1,As1h1]):
//   P0: vmcnt(4) retires this tile's 4 s0 loads (leaves its 4 s1 loads);
//       s_barrier => ALL waves' s0 loads landed; issue t+1 idx{0,1};
//       read A m0..3/s0 + B s0; 16 MFMA.
//   P1: issue {2,3}; read A m4..7/s0; 16 MFMA (B s0 frags reused from regs).
//   P2: vmcnt(4) retires the 4 s1 loads (leaves t+1's {0..3}); barrier;
//       issue {4,5}; read A m0..3/s1 + B s1; MFMA.
//   P3: issue {6,7}; read A m4..7/s1; MFMA.
// vmcnt never drains to 0 in the steady loop (T4). Last tile peeled
// (P2 uses vmcnt(0)). GLDS writes of t+1 land in the buffer whose readers
// (tile t-1) are >= 2 barriers + VMEM-latency behind -- no WAR window.
// BN=128: B has one 128-row half; 6 loads/tile, order
// [As0h0,Bs0,As0h1, As1h0,Bs1,As1h1], vmcnt(3)/(3), issues {0,1}{2}{3,4}{5}.
// MODE 0: bf16 out; col<2048 -> Cb[row][2048]; col>=2048 (V third) written
//         TRANSPOSED into Vt[(b*8+h)*128+d][t].  MODE 1: f32 out Cf[row][N].
#define GLDS(gp, lp)                                                        \
  __builtin_amdgcn_global_load_lds(                                         \
      (const __attribute__((address_space(1))) void*)(gp),                  \
      (__attribute__((address_space(3))) void*)(lp), 16, 0, 0)

#define BAR asm volatile("s_barrier" ::: "memory")

template <int MODE, int BN>
__global__ __launch_bounds__(512, 2)
void k_gemm(const unsigned short* __restrict__ A,   // [M][K] bf16
            const unsigned short* __restrict__ Bt,  // [N][K] bf16
            unsigned short* __restrict__ Cb,        // bf16 out (MODE 0, q|k part)
            unsigned short* __restrict__ Vt,        // bf16 out (MODE 0, v part, transposed)
            float* __restrict__ Cf,                 // f32 out  (MODE 1)
            int M, int N, int K) {
  constexpr int WN = BN / 4;          // wave n-width
  constexpr int NF = WN / 16;         // n-frags per wave (4 or 2)
  constexpr int BSLICE = BN * 64;     // B slice bytes
  constexpr int HALF = 32768 + BN * 128;
  __shared__ __align__(16) unsigned char smem[2 * HALF];
  const int tid = threadIdx.x;
  const int lane = tid & 63;
  const int w = tid >> 6;             // wave 0..7
  const int wm = w >> 2, wn = w & 3;  // 2 x 4

  // XCD-aware bijective swizzle (grids are multiples of 8)
  const int nwg = gridDim.x * gridDim.y;
  int flat = blockIdx.y * gridDim.x + blockIdx.x;
  flat = (flat & 7) * (nwg >> 3) + (flat >> 3);
  const int bx = flat % gridDim.x;
  const int by = flat / gridDim.x;

  // staging addressing
  const int r2 = lane >> 2;
  const int cg = ((lane & 3) ^ ((lane >> 3) & 3)) * 8;  // pre-swizzled col-group

#define IA(q_, kt_, s_, h_)                                                      \
  GLDS(A + (size_t)(by * 256 + (h_)*128 + w * 16 + r2) * K + (kt_)*64 + (s_)*32 + cg, \
       smem + (q_)*HALF + (s_)*16384 + ((h_)*128 + w * 16) * 64)
#define IB(q_, kt_, s_, h_)                                                      \
  GLDS(Bt + (size_t)(bx * BN + (h_)*128 + w * 16 + r2) * K + (kt_)*64 + (s_)*32 + cg, \
       smem + (q_)*HALF + 32768 + (s_)*BSLICE + ((h_)*128 + w * 16) * 64)

  // fragment read offsets
  const int swz = ((lane >> 4) ^ ((lane >> 1) & 3)) * 16;
  const int aBase = (wm * 128 + (lane & 15)) * 64 + swz;
  const int bBase = 32768 + (wn * WN + (lane & 15)) * 64 + swz;

  f32x4_t acc[8][NF];
#pragma unroll
  for (int m = 0; m < 8; ++m)
#pragma unroll
    for (int n = 0; n < NF; ++n) acc[m][n] = (f32x4_t){0.f, 0.f, 0.f, 0.f};
  bf16x8_t af[4], bfr[NF];
  const unsigned char* bp;

#define PHASE(s_, mq_, DO_B)                                                     \
  {                                                                              \
    _Pragma("unroll") for (int m = 0; m < 4; ++m)                                \
        af[m] = *(const bf16x8_t*)(bp + (s_)*16384 + aBase + ((mq_)*4 + m) * 1024); \
    if (DO_B) {                                                                  \
      _Pragma("unroll") for (int n = 0; n < NF; ++n)                             \
          bfr[n] = *(const bf16x8_t*)(bp + (s_)*BSLICE + bBase + n * 1024);      \
    }                                                                            \
    __builtin_amdgcn_s_setprio(1);                                               \
    _Pragma("unroll") for (int m = 0; m < 4; ++m)                                \
        _Pragma("unroll") for (int n = 0; n < NF; ++n)                           \
            acc[(mq_)*4 + m][n] = __builtin_amdgcn_mfma_f32_16x16x32_bf16(       \
                af[m], bfr[n], acc[(mq_)*4 + m][n], 0, 0, 0);                    \
    __builtin_amdgcn_s_setprio(0);                                               \
  }
#define VMC_S                                                                    \
  do {                                                                           \
    if (BN == 256) asm volatile("s_waitcnt vmcnt(4)" ::: "memory");              \
    else           asm volatile("s_waitcnt vmcnt(3)" ::: "memory");              \
  } while (0)

  const int nt = K >> 6;  // K-tiles of 64
  // prologue: stage tile 0 into buf 0 (ledger order)
  if (BN == 256) {
    IA(0, 0, 0, 0); IB(0, 0, 0, 0); IB(0, 0, 0, 1); IA(0, 0, 0, 1);
    IA(0, 0, 1, 0); IB(0, 0, 1, 0); IB(0, 0, 1, 1); IA(0, 0, 1, 1);
  } else {
    IA(0, 0, 0, 0); IB(0, 0, 0, 0); IA(0, 0, 0, 1);
    IA(0, 0, 1, 0); IB(0, 0, 1, 0); IA(0, 0, 1, 1);
  }
#pragma unroll 1
  for (int t = 0; t < nt - 1; ++t) {
    const int p = t & 1, q = p ^ 1;
    const int kn = t + 1;
    bp = smem + p * HALF;
    // ---- P0
    VMC_S; BAR;
    IA(q, kn, 0, 0); IB(q, kn, 0, 0);
    PHASE(0, 0, true);
    // ---- P1
    if (BN == 256) { IB(q, kn, 0, 1); IA(q, kn, 0, 1); }
    else           { IA(q, kn, 0, 1); }
    PHASE(0, 1, false);
    // ---- P2
    VMC_S; BAR;
    IA(q, kn, 1, 0); IB(q, kn, 1, 0);
    PHASE(1, 0, true);
    // ---- P3
    if (BN == 256) { IB(q, kn, 1, 1); IA(q, kn, 1, 1); }
    else           { IA(q, kn, 1, 1); }
    PHASE(1, 1, false);
  }
  // peeled last tile (drain)
  {
    bp = smem + ((nt - 1) & 1) * HALF;
    VMC_S; BAR;
    PHASE(0, 0, true);
    PHASE(0, 1, false);
    asm volatile("s_waitcnt vmcnt(0)" ::: "memory"); BAR;
    PHASE(1, 0, true);
    PHASE(1, 1, false);
  }

  // C/D layout (m89-verified): col = lane&15, row = (lane>>4)*4 + reg
  const int row0 = by * 256 + wm * 128 + ((lane >> 4) << 2);
  const int col0 = bx * BN + wn * WN + (lane & 15);
  if (MODE == 1) {
#pragma unroll
    for (int m = 0; m < 8; ++m)
#pragma unroll
      for (int n = 0; n < NF; ++n)
#pragma unroll
        for (int r = 0; r < 4; ++r)
          Cf[(size_t)(row0 + m * 16 + r) * N + col0 + n * 16] = acc[m][n][r];
  } else if (bx * BN < 2048) {
#pragma unroll
    for (int m = 0; m < 8; ++m)
#pragma unroll
      for (int n = 0; n < NF; ++n)
#pragma unroll
        for (int r = 0; r < 4; ++r)
          Cb[(size_t)(row0 + m * 16 + r) * 2048 + col0 + n * 16] = f2bf(acc[m][n][r]);
  } else {
#pragma unroll
    for (int m = 0; m < 8; ++m)
#pragma unroll
      for (int n = 0; n < NF; ++n)
#pragma unroll
        for (int r = 0; r < 4; ++r) {
          const int row = row0 + m * 16 + r;
          const int vcol = col0 + n * 16 - 2048;
          const int hh = vcol >> 7, dd = vcol & 127;
          const int bb = row >> 11, tt = row & 2047;
          Vt[((size_t)(bb * NHEAD + hh) * 128 + dd) * TSEQ + tt] = f2bf(acc[m][n][r]);
        }
  }
#undef IA
#undef IB
#undef PHASE
#undef VMC_S
}

// ---------- in-place RMSNorm on q (cols 0..1023) and k (cols 1024..2047) ----------
__global__ __launch_bounds__(256)
void k_rmsnorm(unsigned short* __restrict__ qk, const float* __restrict__ qw,
               const float* __restrict__ kw) {
  const int row = blockIdx.x;
  const int tid = threadIdx.x;
  unsigned short* base = qk + (size_t)row * 2048;
  uint2 uq = *(const uint2*)(base + tid * 4);
  uint2 uk = *(const uint2*)(base + 1024 + tid * 4);
  float q0 = bflo(uq.x), q1 = bfhi(uq.x), q2 = bflo(uq.y), q3 = bfhi(uq.y);
  float k0 = bflo(uk.x), k1 = bfhi(uk.x), k2 = bflo(uk.y), k3 = bfhi(uk.y);
  float sq = q0 * q0 + q1 * q1 + q2 * q2 + q3 * q3;
  float sk = k0 * k0 + k1 * k1 + k2 * k2 + k3 * k3;
#pragma unroll
  for (int off = 32; off > 0; off >>= 1) {
    sq += __shfl_xor(sq, off);
    sk += __shfl_xor(sk, off);
  }
  __shared__ float red[8];
  const int w = tid >> 6;
  if ((tid & 63) == 0) { red[w] = sq; red[4 + w] = sk; }
  __syncthreads();
  sq = red[0] + red[1] + red[2] + red[3];
  sk = red[4] + red[5] + red[6] + red[7];
  const float rq = rsqrtf(sq * (1.0f / 1024.0f) + 1e-6f);
  const float rk = rsqrtf(sk * (1.0f / 1024.0f) + 1e-6f);
  const int c = tid * 4;
  uint2 oq, ok;
  oq.x = (unsigned)f2bf(q0 * rq * qw[c]) | ((unsigned)f2bf(q1 * rq * qw[c + 1]) << 16);
  oq.y = (unsigned)f2bf(q2 * rq * qw[c + 2]) | ((unsigned)f2bf(q3 * rq * qw[c + 3]) << 16);
  ok.x = (unsigned)f2bf(k0 * rk * kw[c]) | ((unsigned)f2bf(k1 * rk * kw[c + 1]) << 16);
  ok.y = (unsigned)f2bf(k2 * rk * kw[c + 2]) | ((unsigned)f2bf(k3 * rk * kw[c + 3]) << 16);
  *(uint2*)(base + tid * 4) = oq;
  *(uint2*)(base + 1024 + tid * 4) = ok;
}

// ---------- MFMA sliding-window ALiBi attention ----------
// One wave per 16 queries of one (b,h). Key window: 32 keys [t0-16, t0+16).
// Swapped QK^T (A=K, B=Q) -> S^T: lane holds query c=lane&15, keys g*4+r (+16).
// Softmax: in-lane over 8 + shfl_xor(16,32). P -> padded LDS -> A-frag for PV.
// V read from transposed Vt buffer as b128 B-frags.
__global__ __launch_bounds__(256)
void k_attn(const unsigned short* __restrict__ qk,   // [8192][2048] q|k (normalized)
            const unsigned short* __restrict__ vt,   // [(b*8+h)*128+d][2048]
            unsigned short* __restrict__ outb) {     // [8192][1024] bf16
  __shared__ __align__(16) unsigned char plds_all[4][1280];  // 16 rows x 80B (40 elems)
  const int lane = threadIdx.x & 63;
  const int wv = threadIdx.x >> 6;
  unsigned char* plds = plds_all[wv];
  const int bh = blockIdx.y;                 // 0..31
  const int b = bh >> 3, h = bh & 7;
  const int t0 = blockIdx.x * 64 + wv * 16;
  const int g = lane >> 4, c = lane & 15;
  const int jlo = t0 - 16;

  // Q B-fragments: Q[t0+c][kc*32 + g*8 .. +8]
  const unsigned short* qrow = qk + (size_t)(b * TSEQ + t0 + c) * 2048 + h * 128 + g * 8;
  bf16x8_t qf[4];
#pragma unroll
  for (int kc = 0; kc < 4; ++kc) qf[kc] = *(const bf16x8_t*)(qrow + kc * 32);

  // K A-fragments (2 key-tiles); clamp negative rows (masked anyway)
  const int j0 = jlo + c;
  const int j0c = (j0 < 0) ? 0 : j0;
  const unsigned short* krow0 = qk + (size_t)(b * TSEQ + j0c) * 2048 + 1024 + h * 128 + g * 8;
  const unsigned short* krow1 = qk + (size_t)(b * TSEQ + t0 + c) * 2048 + 1024 + h * 128 + g * 8;
  bf16x8_t kf0[4], kf1[4];
#pragma unroll
  for (int kc = 0; kc < 4; ++kc) {
    kf0[kc] = *(const bf16x8_t*)(krow0 + kc * 32);
    kf1[kc] = *(const bf16x8_t*)(krow1 + kc * 32);
  }

  f32x4_t s0 = (f32x4_t){0.f, 0.f, 0.f, 0.f};
  f32x4_t s1 = (f32x4_t){0.f, 0.f, 0.f, 0.f};
#pragma unroll
  for (int kc = 0; kc < 4; ++kc) {
    s0 = __builtin_amdgcn_mfma_f32_16x16x32_bf16(kf0[kc], qf[kc], s0, 0, 0, 0);
    s1 = __builtin_amdgcn_mfma_f32_16x16x32_bf16(kf1[kc], qf[kc], s1, 0, 0, 0);
  }

  // scores + mask + bias. key kk = z*16 + g*4 + r; query = c; rel = kk-16-c.
  const float scale = 0.08838834764831845f;  // 1/sqrt(128)
  const float slope = 1.0f / (float)(1 << h);
  float val[8];
#pragma unroll
  for (int z = 0; z < 2; ++z)
#pragma unroll
    for (int r = 0; r < 4; ++r) {
      const int kk = z * 16 + g * 4 + r;
      const int rel = kk - 16 - c;
      const bool ok = (rel <= 0) & (rel >= -WIN) & (jlo + kk >= 0);
      const float sc = (z == 0) ? s0[r] : s1[r];
      val[z * 4 + r] = ok ? (sc * scale + slope * (float)rel) : -1.0e30f;
    }
  float m = val[0];
#pragma unroll
  for (int i = 1; i < 8; ++i) m = fmaxf(m, val[i]);
  m = fmaxf(m, __shfl_xor(m, 16));
  m = fmaxf(m, __shfl_xor(m, 32));
  float e[8], s = 0.f;
#pragma unroll
  for (int i = 0; i < 8; ++i) { e[i] = __expf(val[i] - m); s += e[i]; }
  s += __shfl_xor(s, 16);
  s += __shfl_xor(s, 32);
  const float inv = 1.0f / s;

  // P -> LDS [query c][key kk], row stride 40 elems (80B): 2-way banks = free
#pragma unroll
  for (int z = 0; z < 2; ++z) {
    uint2 pk;
    pk.x = (unsigned)f2bf(e[z * 4 + 0] * inv) | ((unsigned)f2bf(e[z * 4 + 1] * inv) << 16);
    pk.y = (unsigned)f2bf(e[z * 4 + 2] * inv) | ((unsigned)f2bf(e[z * 4 + 3] * inv) << 16);
    *(uint2*)(plds + c * 80 + z * 32 + g * 8) = pk;
  }
  // A-fragment of P: row=c (query), keys g*8..+8
  const bf16x8_t pf = *(const bf16x8_t*)(plds + c * 80 + g * 16);

  // PV: B-frag = V[jlo + g*8 + i][d0 + c] = Vt[d0+c][jlo + g*8 ...]
  const int vc0 = jlo + g * 8;
  const int vcc = (vc0 < 0) ? 0 : vc0;   // garbage rows get zero weight
  const unsigned short* vbase = vt + (size_t)(bh * 128 + c) * TSEQ + vcc;
  unsigned short* orow = outb + (size_t)(b * TSEQ + t0) * 1024 + h * 128 + c;
#pragma unroll
  for (int n = 0; n < 8; ++n) {
    const bf16x8_t vf = *(const bf16x8_t*)(vbase + (size_t)n * 16 * TSEQ);
    f32x4_t o = __builtin_amdgcn_mfma_f32_16x16x32_bf16(pf, vf, (f32x4_t){0.f, 0.f, 0.f, 0.f},
                                                        0, 0, 0);
    // C: row=(g*4+r)=query, col=c=d within chunk n
#pragma unroll
    for (int r = 0; r < 4; ++r)
      orow[(size_t)(g * 4 + r) * 1024 + n * 16] = f2bf(o[r]);
  }
}

extern "C" void kernel_launch(void* const* d_in, const int* in_sizes, int n_in,
                              void* d_out, int out_size, void* d_ws, size_t ws_size,
                              hipStream_t stream) {
  const float* x = (const float*)d_in[0];
  const float* wq = (const float*)d_in[1];
  const float* wk = (const float*)d_in[2];
  const float* wv = (const float*)d_in[3];
  const float* wo = (const float*)d_in[4];
  const float* qnw = (const float*)d_in[5];
  const float* knw = (const float*)d_in[6];
  float* out = (float*)d_out;

  const int M = 4 * TSEQ;  // 8192 rows
  // workspace (75.5 MB):
  //   xb  [M][1024] bf16 (16.8 MB)  -- x bf16; later reused as attention output
  //   Wt  [4][1024][1024] bf16 (8.4 MB)
  //   qk  [M][2048] bf16 (33.5 MB)  -- q|k (normalized in place)
  //   Vt  [32][128][2048] bf16 (16.8 MB) -- V transposed per (b,h)
  unsigned short* xb = (unsigned short*)d_ws;
  unsigned short* Wt = xb + (size_t)M * DIMW;
  unsigned short* qkb = Wt + (size_t)4 * DIMW * DIMW;
  unsigned short* Vt = qkb + (size_t)M * 2048;
  if (ws_size < ((size_t)M * DIMW + (size_t)4 * DIMW * DIMW + (size_t)M * 2048 +
                 (size_t)M * 2048) * 2) return;

  k_conv_x<<<(M * DIMW / 4 + 255) / 256, 256, 0, stream>>>(x, xb, M * DIMW / 4);
  k_conv_w<<<dim3(32, 32, 4), dim3(32, 8), 0, stream>>>(wq, wk, wv, wo, Wt);
  k_gemm<0, 256><<<dim3(12, 32), 512, 0, stream>>>(xb, Wt, qkb, Vt, nullptr, M, 3072, 1024);
  k_rmsnorm<<<M, 256, 0, stream>>>(qkb, qnw, knw);
  k_attn<<<dim3(TSEQ / 64, 32), 256, 0, stream>>>(qkb, Vt, xb);  // xb = attn out
  k_gemm<1, 128><<<dim3(8, 32), 512, 0, stream>>>(xb, Wt + (size_t)3 * DIMW * DIMW, nullptr,
                                                  nullptr, out, M, 1024, 1024);
}